// Round 9
// baseline (167.661 us; speedup 1.0000x reference)
//
#include <hip/hip_runtime.h>
#include <math.h>

// Problem constants (fixed by setup_inputs): B=4096, T=512, Q=4
#define T_DIM 512
#define GAMMA_F 0.997f
#define EPS_F 1e-3f
// log2(0.997)
#define LOG2_GAMMA (-0.0043345907f)

typedef float v4f __attribute__((ext_vector_type(4)));

__device__ __forceinline__ float inv_rescale_f(float x) {
    float s = (x > 0.f) ? 1.f : ((x < 0.f) ? -1.f : 0.f);
    float sqrt_arg = 1.f + 4.f * EPS_F * (fabsf(x) + 1.f + EPS_F);
    float q = (sqrtf(sqrt_arg) - 1.f) * (1.f / (2.f * EPS_F));
    return s * (q * q - 1.f);
}

__device__ __forceinline__ float rescale_f(float x) {
    return copysignf(sqrtf(fabsf(x) + 1.f) - 1.f, x) + EPS_F * x;
}

// R11: R7's load/compute structure (the ONLY variant to exceed 2.9 TB/s;
// R0/R6/R8/R9/R10 all pin at 1.9-2.1) with its one defect fixed: the stores.
// R7's per-thread 4x dwordx4 stores put lanes at 64B stride -> every store
// instruction wrote 16B fragments of 64 lines -> WRITE 57.9MB (1.76x ideal)
// and ~+60MB FETCH from fetch-on-partial-write + dirty-line churn. Fix:
// per-wave LDS transpose (stride-5 slots: write phase conflict-free, read
// phase <=3-way), then 4 fully-coalesced dwordx4 stores covering complete
// 64B lines. No s_barrier anywhere (wave-synchronous lgkmcnt only), loads
// and arithmetic byte-identical to the harness-passed R7.
__global__ __launch_bounds__(256) void nstep_qloss_kernel(
    const float* __restrict__ cur_q,    // (B,T,4)
    const float* __restrict__ next_q,   // (B,T,4)
    const float* __restrict__ log_p,    // (B,T)
    const float* __restrict__ reward,   // (B,T,4)
    const float* __restrict__ is_done,  // (B,T)
    const float* __restrict__ mask,     // (B,T)
    float* __restrict__ out,            // (B,T,4)
    int BT)
{
    __shared__ v4f slds[4][320];        // per-wave 64 lanes x 5 slots (1 pad)

    const int cid = blockIdx.x * 256 + threadIdx.x;   // chunk id: 4 t's per chunk
    if (cid * 4 >= BT) return;
    const int lane = threadIdx.x & 63;
    const int wv   = threadIdx.x >> 6;
    const int b    = cid >> 7;                        // 128 chunks per row
    const int t0   = (cid & 127) << 2;
    const int base = b * T_DIM;

    // clamped halo t-indices u=4..7 (only the t0==508 chunk actually clamps)
    const int h4 = (t0 + 4 < T_DIM) ? t0 + 4 : T_DIM - 1;
    const int h5 = (t0 + 5 < T_DIM) ? t0 + 5 : T_DIM - 1;
    const int h6 = (t0 + 6 < T_DIM) ? t0 + 6 : T_DIM - 1;
    const int h7 = (t0 + 7 < T_DIM) ? t0 + 7 : T_DIM - 1;
    // validity of halo taps (owned taps u=0..3 always valid)
    const float va4 = (t0 + 4 < T_DIM) ? 1.f : 0.f;
    const float va5 = (t0 + 5 < T_DIM) ? 1.f : 0.f;
    const float va6 = (t0 + 6 < T_DIM) ? 1.f : 0.f;
    const float va7 = (t0 + 7 < T_DIM) ? 1.f : 0.f;

    const v4f* rew4 = (const v4f*)reward;
    const v4f* nq4  = (const v4f*)next_q;
    const v4f* cq4  = (const v4f*)cur_q;
    v4f*       out4 = (v4f*)out;

    // ---------------- load block (identical to R7) ----------------
    v4f m_o = *(const v4f*)(mask    + base + t0);   // mask[t0..t0+3]
    v4f d_o = *(const v4f*)(is_done + base + t0);
    v4f p_o = *(const v4f*)(log_p   + base + t0);
    float mh4 = mask[base + h4], mh5 = mask[base + h5], mh6 = mask[base + h6], mh7 = mask[base + h7];
    float dh4 = is_done[base + h4], dh5 = is_done[base + h5], dh6 = is_done[base + h6], dh7 = is_done[base + h7];
    float ph4 = log_p[base + h4], ph5 = log_p[base + h5], ph6 = log_p[base + h6], ph7 = log_p[base + h7];
    v4f r0 = rew4[base + t0];
    v4f r1 = rew4[base + t0 + 1];
    v4f r2 = rew4[base + t0 + 2];
    v4f r3 = rew4[base + t0 + 3];
    v4f r4 = rew4[base + h4];
    v4f r5 = rew4[base + h5];
    v4f r6 = rew4[base + h6];
    v4f r7 = rew4[base + h7];
    v4f n0 = nq4[base + h4];                         // next_q at s4 of t0+j
    v4f n1 = nq4[base + h5];
    v4f n2 = nq4[base + h6];
    v4f n3 = nq4[base + h7];
    v4f c0 = cq4[base + t0];
    v4f c1 = cq4[base + t0 + 1];
    v4f c2 = cq4[base + t0 + 2];
    v4f c3 = cq4[base + t0 + 3];

    // ---------------- per-tap pre-combined operands ----------------
    float md4 = mh4 * (1.f - dh4);
    float md5 = mh5 * (1.f - dh5);
    float md6 = mh6 * (1.f - dh6);
    float md7 = mh7 * (1.f - dh7);
    float lz0 = m_o.x * (1.f - d_o.x) * p_o.x;
    float lz1 = m_o.y * (1.f - d_o.y) * p_o.y;
    float lz2 = m_o.z * (1.f - d_o.z) * p_o.z;
    float lz3 = m_o.w * (1.f - d_o.w) * p_o.w;
    float lz4 = va4 * md4 * ph4;
    float lz5 = va5 * md5 * ph5;
    float lz6 = va6 * md6 * ph6;
    float lz7 = va7 * md7 * ph7;
    float w0 = m_o.x, w1 = m_o.y, w2 = m_o.z, w3 = m_o.w;
    float w4 = va4 * mh4, w5 = va5 * mh5, w6 = va6 * mh6, w7 = va7 * mh7;
    float x0 = w0 * r0.x, y0 = w0 * r0.y, z0 = w0 * r0.w;
    float x1 = w1 * r1.x, y1 = w1 * r1.y, z1 = w1 * r1.w;
    float x2 = w2 * r2.x, y2 = w2 * r2.y, z2 = w2 * r2.w;
    float x3 = w3 * r3.x, y3 = w3 * r3.y, z3 = w3 * r3.w;
    float x4 = w4 * r4.x, y4 = w4 * r4.y, z4 = w4 * r4.w;
    float x5 = w5 * r5.x, y5 = w5 * r5.y, z5 = w5 * r5.w;
    float x6 = w6 * r6.x, y6 = w6 * r6.y, z6 = w6 * r6.w;
    float x7 = w7 * r7.x, y7 = w7 * r7.y, z7 = w7 * r7.w;

    const float g1 = GAMMA_F;
    const float g2 = g1 * g1;
    const float g3 = g2 * g1;
    const float g4 = g2 * g2;
    const float LSC = GAMMA_F * (1.f / 3.f);   // extra gamma * inv_num_q

    // ---------------- per-output j = 0..3 (identical to R7) ----------------
    float a0 = x0; a0 = fmaf(g1, x1, a0); a0 = fmaf(g2, x2, a0); a0 = fmaf(g3, x3, a0); a0 = fmaf(g4, x4, a0);
    float b0 = y0; b0 = fmaf(g1, y1, b0); b0 = fmaf(g2, y2, b0); b0 = fmaf(g3, y3, b0); b0 = fmaf(g4, y4, b0);
    float e0 = z0; e0 = fmaf(g1, z1, e0); e0 = fmaf(g2, z2, e0); e0 = fmaf(g3, z3, e0); e0 = fmaf(g4, z4, e0);
    float L0 = lz0; L0 = fmaf(g1, lz1, L0); L0 = fmaf(g2, lz2, L0); L0 = fmaf(g3, lz3, L0); L0 = fmaf(g4, lz4, L0);
    L0 *= LSC;
    float a1 = x1; a1 = fmaf(g1, x2, a1); a1 = fmaf(g2, x3, a1); a1 = fmaf(g3, x4, a1); a1 = fmaf(g4, x5, a1);
    float b1 = y1; b1 = fmaf(g1, y2, b1); b1 = fmaf(g2, y3, b1); b1 = fmaf(g3, y4, b1); b1 = fmaf(g4, y5, b1);
    float e1 = z1; e1 = fmaf(g1, z2, e1); e1 = fmaf(g2, z3, e1); e1 = fmaf(g3, z4, e1); e1 = fmaf(g4, z5, e1);
    float L1 = lz1; L1 = fmaf(g1, lz2, L1); L1 = fmaf(g2, lz3, L1); L1 = fmaf(g3, lz4, L1); L1 = fmaf(g4, lz5, L1);
    L1 *= LSC;
    float a2 = x2; a2 = fmaf(g1, x3, a2); a2 = fmaf(g2, x4, a2); a2 = fmaf(g3, x5, a2); a2 = fmaf(g4, x6, a2);
    float b2 = y2; b2 = fmaf(g1, y3, b2); b2 = fmaf(g2, y4, b2); b2 = fmaf(g3, y5, b2); b2 = fmaf(g4, y6, b2);
    float e2 = z2; e2 = fmaf(g1, z3, e2); e2 = fmaf(g2, z4, e2); e2 = fmaf(g3, z5, e2); e2 = fmaf(g4, z6, e2);
    float L2 = lz2; L2 = fmaf(g1, lz3, L2); L2 = fmaf(g2, lz4, L2); L2 = fmaf(g3, lz5, L2); L2 = fmaf(g4, lz6, L2);
    L2 *= LSC;
    float a3 = x3; a3 = fmaf(g1, x4, a3); a3 = fmaf(g2, x5, a3); a3 = fmaf(g3, x6, a3); a3 = fmaf(g4, x7, a3);
    float b3 = y3; b3 = fmaf(g1, y4, b3); b3 = fmaf(g2, y5, b3); b3 = fmaf(g3, y6, b3); b3 = fmaf(g4, y7, b3);
    float e3 = z3; e3 = fmaf(g1, z4, e3); e3 = fmaf(g2, z5, e3); e3 = fmaf(g3, z6, e3); e3 = fmaf(g4, z7, e3);
    float L3 = lz3; L3 = fmaf(g1, lz4, L3); L3 = fmaf(g2, lz5, L3); L3 = fmaf(g3, lz6, L3); L3 = fmaf(g4, lz7, L3);
    L3 *= LSC;

    float q0 = exp2f((float)h4 * LOG2_GAMMA) * md4;
    float q1 = exp2f((float)h5 * LOG2_GAMMA) * md5;
    float q2 = exp2f((float)h6 * LOG2_GAMMA) * md6;
    float q3 = exp2f((float)h7 * LOG2_GAMMA) * md7;

    v4f o0, o1, o2, o3;
    {
        float tx = rescale_f(a0 + q0 * inv_rescale_f(n0.x) + 1.0f * L0);
        float ty = rescale_f(b0 + q0 * inv_rescale_f(n0.y) + 2.0f * L0);
        float tw = rescale_f(e0 + q0 * inv_rescale_f(n0.w) + 0.5f * L0);
        float hm = 0.5f * m_o.x;
        float u0 = c0.x - tx, u1 = c0.y - ty, u3 = c0.w - tw;
        o0.x = hm * u0 * u0; o0.y = hm * 0.5f * u1 * u1; o0.z = 0.f; o0.w = hm * 2.0f * u3 * u3;
    }
    {
        float tx = rescale_f(a1 + q1 * inv_rescale_f(n1.x) + 1.0f * L1);
        float ty = rescale_f(b1 + q1 * inv_rescale_f(n1.y) + 2.0f * L1);
        float tw = rescale_f(e1 + q1 * inv_rescale_f(n1.w) + 0.5f * L1);
        float hm = 0.5f * m_o.y;
        float u0 = c1.x - tx, u1 = c1.y - ty, u3 = c1.w - tw;
        o1.x = hm * u0 * u0; o1.y = hm * 0.5f * u1 * u1; o1.z = 0.f; o1.w = hm * 2.0f * u3 * u3;
    }
    {
        float tx = rescale_f(a2 + q2 * inv_rescale_f(n2.x) + 1.0f * L2);
        float ty = rescale_f(b2 + q2 * inv_rescale_f(n2.y) + 2.0f * L2);
        float tw = rescale_f(e2 + q2 * inv_rescale_f(n2.w) + 0.5f * L2);
        float hm = 0.5f * m_o.z;
        float u0 = c2.x - tx, u1 = c2.y - ty, u3 = c2.w - tw;
        o2.x = hm * u0 * u0; o2.y = hm * 0.5f * u1 * u1; o2.z = 0.f; o2.w = hm * 2.0f * u3 * u3;
    }
    {
        float tx = rescale_f(a3 + q3 * inv_rescale_f(n3.x) + 1.0f * L3);
        float ty = rescale_f(b3 + q3 * inv_rescale_f(n3.y) + 2.0f * L3);
        float tw = rescale_f(e3 + q3 * inv_rescale_f(n3.w) + 0.5f * L3);
        float hm = 0.5f * m_o.w;
        float u0 = c3.x - tx, u1 = c3.y - ty, u3 = c3.w - tw;
        o3.x = hm * u0 * u0; o3.y = hm * 0.5f * u1 * u1; o3.z = 0.f; o3.w = hm * 2.0f * u3 * u3;
    }

    // ---------------- wave-local transpose -> coalesced stores ----------------
    // write: lane L owns slots [5L, 5L+4): bank-quad starts {0,20,8,28,16,4,24,12}
    // per 8 lanes -> all 32 banks tiled once -> conflict-free.
    slds[wv][5 * lane + 0] = o0;
    slds[wv][5 * lane + 1] = o1;
    slds[wv][5 * lane + 2] = o2;
    slds[wv][5 * lane + 3] = o3;
    asm volatile("s_waitcnt lgkmcnt(0)" ::: "memory");   // wave-sync (no s_barrier)
    __builtin_amdgcn_sched_barrier(0);                   // rule #18

    // wave-uniform output base: first chunk of this wave
    const int bcid   = cid & ~63;
    const int wbase4 = (bcid >> 7) * T_DIM + ((bcid & 127) << 2);
    #pragma unroll
    for (int j = 0; j < 4; ++j) {
        // element n = 64j+lane of the wave's 256 contiguous outputs:
        // computed by in-wave chunk (n>>2) at slot (n&3)
        v4f v = slds[wv][80 * j + 5 * (lane >> 2) + (lane & 3)];
        out4[wbase4 + 64 * j + lane] = v;                // full-line coalesced
    }
}

extern "C" void kernel_launch(void* const* d_in, const int* in_sizes, int n_in,
                              void* d_out, int out_size, void* d_ws, size_t ws_size,
                              hipStream_t stream) {
    const float* cur_q   = (const float*)d_in[0];
    const float* next_q  = (const float*)d_in[1];
    const float* log_p   = (const float*)d_in[2];
    const float* reward  = (const float*)d_in[3];
    const float* is_done = (const float*)d_in[4];
    const float* mask    = (const float*)d_in[5];
    float* out = (float*)d_out;

    int BT = in_sizes[2];                   // B*T (element count)
    int chunks = BT / 4;                    // 4 t's per thread
    int blocks = (chunks + 255) / 256;      // 2048 for B=4096,T=512
    hipLaunchKernelGGL(nstep_qloss_kernel, dim3(blocks), dim3(256), 0, stream,
                       cur_q, next_q, log_p, reward, is_done, mask, out, BT);
}

// Round 10
// 160.505 us; speedup vs baseline: 1.0446x; 1.0446x over previous
//
#include <hip/hip_runtime.h>
#include <math.h>

// Problem constants (fixed by setup_inputs): B=4096, T=512, Q=4
#define T_DIM 512
#define GAMMA_F 0.997f
#define EPS_F 1e-3f
// log2(0.997)
#define LOG2_GAMMA (-0.0043345907f)

typedef float v4f __attribute__((ext_vector_type(4)));

__device__ __forceinline__ float inv_rescale_f(float x) {
    float s = (x > 0.f) ? 1.f : ((x < 0.f) ? -1.f : 0.f);
    float sqrt_arg = 1.f + 4.f * EPS_F * (fabsf(x) + 1.f + EPS_F);
    float q = (sqrtf(sqrt_arg) - 1.f) * (1.f / (2.f * EPS_F));
    return s * (q * q - 1.f);
}

__device__ __forceinline__ float rescale_f(float x) {
    return copysignf(sqrtf(fabsf(x) + 1.f) - 1.f, x) + EPS_F * x;
}

// R12 = R0 (the empirical best: 46-47us dispatch, 157.1us headline) + ONE
// variable: non-temporal output stores.
// Session ledger: seven structurally distinct designs (R0 one-shot scalar,
// R6 LDS row-staging, R7 register-halo chunks, R8 persistent dbuf, R9
// asm-forced 22-deep MLP, R10 persistent barrier-free shuffle pipeline, R11
// R7+coalesced-store transpose) ALL pin at 2.05-2.10 TB/s counted HBM with
// clean traffic. R7's apparent 2.9 TB/s was junk partial-line write churn
// (R11 removed it: WRITE 57.9->32.8 ideal, rate fell back to 2.06).
// FETCH=62.7MB is half the 125.8MB unique input (rest L3-resident from the
// harness restore), so delivered BW ~3.4 TB/s. The 2.05 TB/s HBM service
// rate is invariant to MLP depth / persistence / barriers / LDS / store
// pattern => structural ceiling for this dispatch environment. nt stores
// keep the never-re-read output from evicting L3-resident inputs.
__global__ __launch_bounds__(256) void nstep_qloss_kernel(
    const float* __restrict__ cur_q,    // (B,T,4)
    const float* __restrict__ next_q,   // (B,T,4)
    const float* __restrict__ log_p,    // (B,T)
    const float* __restrict__ reward,   // (B,T,4)
    const float* __restrict__ is_done,  // (B,T)
    const float* __restrict__ mask,     // (B,T)
    float* __restrict__ out,            // (B,T,4)
    int BT)
{
    int idx = blockIdx.x * 256 + threadIdx.x;
    if (idx >= BT) return;
    int t = idx & (T_DIM - 1);
    int base = idx - t;                 // b*T

    // ---- all address math first ----
    int s1 = (t + 1 < T_DIM) ? t + 1 : T_DIM - 1;
    int s2 = (t + 2 < T_DIM) ? t + 2 : T_DIM - 1;
    int s3 = (t + 3 < T_DIM) ? t + 3 : T_DIM - 1;
    int s4 = (t + 4 < T_DIM) ? t + 4 : T_DIM - 1;
    int o0 = idx;
    int o1 = base + s1, o2 = base + s2, o3 = base + s3, o4 = base + s4;

    const v4f* rew4 = (const v4f*)reward;
    const v4f* nq4  = (const v4f*)next_q;
    const v4f* cq4  = (const v4f*)cur_q;
    v4f* out4       = (v4f*)out;

    // ---- load block: 22 independent loads, nothing may sink below the fence ----
    float m0 = mask[o0], m1 = mask[o1], m2 = mask[o2], m3 = mask[o3], m4 = mask[o4];
    float d0 = is_done[o0], d1 = is_done[o1], d2 = is_done[o2], d3 = is_done[o3], d4 = is_done[o4];
    float p0 = log_p[o0], p1 = log_p[o1], p2 = log_p[o2], p3 = log_p[o3], p4 = log_p[o4];
    v4f r0 = rew4[o0], r1 = rew4[o1], r2 = rew4[o2], r3 = rew4[o3], r4 = rew4[o4];
    v4f nq = nq4[o4];
    v4f cq = cq4[o0];
    __builtin_amdgcn_sched_barrier(0);  // pin: all loads issued before any use

    // validity of taps 1..4 (tap 0 always valid)
    float v1 = (t + 1 < T_DIM) ? 1.f : 0.f;
    float v2 = (t + 2 < T_DIM) ? 1.f : 0.f;
    float v3 = (t + 3 < T_DIM) ? 1.f : 0.f;
    float v4v = (t + 4 < T_DIM) ? 1.f : 0.f;

    const float g1 = GAMMA_F;
    const float g2 = g1 * g1;
    const float g3 = g2 * g1;
    const float g4 = g2 * g2;

    float w0 = m0;
    float w1 = v1 * g1 * m1;
    float w2 = v2 * g2 * m2;
    float w3 = v3 * g3 * m3;
    float w4 = v4v * g4 * m4;

    // reward_sum per q
    float a0 = w0 * r0.x; float a1 = w0 * r0.y; float a2 = w0 * r0.z; float a3 = w0 * r0.w;
    a0 = fmaf(w1, r1.x, a0); a1 = fmaf(w1, r1.y, a1); a2 = fmaf(w1, r1.z, a2); a3 = fmaf(w1, r1.w, a3);
    a0 = fmaf(w2, r2.x, a0); a1 = fmaf(w2, r2.y, a1); a2 = fmaf(w2, r2.z, a2); a3 = fmaf(w2, r2.w, a3);
    a0 = fmaf(w3, r3.x, a0); a1 = fmaf(w3, r3.y, a1); a2 = fmaf(w3, r3.z, a2); a3 = fmaf(w3, r3.w, a3);
    a0 = fmaf(w4, r4.x, a0); a1 = fmaf(w4, r4.y, a1); a2 = fmaf(w4, r4.z, a2); a3 = fmaf(w4, r4.w, a3);

    // log_p window sum (q-independent)
    float Ls = w0 * (1.f - d0) * p0;
    Ls = fmaf(w1, (1.f - d1) * p1, Ls);
    Ls = fmaf(w2, (1.f - d2) * p2, Ls);
    Ls = fmaf(w3, (1.f - d3) * p3, Ls);
    Ls = fmaf(w4, (1.f - d4) * p4, Ls);
    Ls *= GAMMA_F * (1.f / 3.f);        // extra gamma factor * inv_num_q

    // next_term: coeff = gamma^i (absolute index, faithful), i = s4
    float coeff = exp2f((float)s4 * LOG2_GAMMA);
    float g = coeff * m4 * (1.f - d4);
    float nt0 = g * inv_rescale_f(nq.x);
    float nt1 = g * inv_rescale_f(nq.y);
    float nt2 = g * inv_rescale_f(nq.z);
    float nt3 = g * inv_rescale_f(nq.w);

    // q_w = {1, 0.5, 0, 2}; inv_qw = {1, 2, 0, 0.5}
    float tgt0 = rescale_f(a0 + nt0 + 1.0f * Ls);
    float tgt1 = rescale_f(a1 + nt1 + 2.0f * Ls);
    float tgt2 = rescale_f(a2 + nt2);
    float tgt3 = rescale_f(a3 + nt3 + 0.5f * Ls);
    (void)tgt2;

    float hm = 0.5f * m0;
    float e0 = cq.x - tgt0;
    float e1 = cq.y - tgt1;
    float e3 = cq.w - tgt3;
    v4f o;
    o.x = hm * e0 * e0;
    o.y = hm * 0.5f * e1 * e1;
    o.z = 0.f;                          // q_w[2] == 0
    o.w = hm * 2.0f * e3 * e3;
    // nt store: output is never re-read in this dispatch; don't let it evict
    // the L3-resident input lines (the source of the 63MB fetch savings).
    __builtin_nontemporal_store(o, &out4[idx]);
}

extern "C" void kernel_launch(void* const* d_in, const int* in_sizes, int n_in,
                              void* d_out, int out_size, void* d_ws, size_t ws_size,
                              hipStream_t stream) {
    const float* cur_q   = (const float*)d_in[0];
    const float* next_q  = (const float*)d_in[1];
    const float* log_p   = (const float*)d_in[2];
    const float* reward  = (const float*)d_in[3];
    const float* is_done = (const float*)d_in[4];
    const float* mask    = (const float*)d_in[5];
    float* out = (float*)d_out;

    int BT = in_sizes[2];               // B*T
    int blocks = (BT + 255) / 256;
    hipLaunchKernelGGL(nstep_qloss_kernel, dim3(blocks), dim3(256), 0, stream,
                       cur_q, next_q, log_p, reward, is_done, mask, out, BT);
}